// Round 1
// baseline (1036.276 us; speedup 1.0000x reference)
//
#include <hip/hip_runtime.h>
#include <math.h>

// Problem constants (OLMoE block): E=32 experts, K=4 top-k, H=2048, F=1024,
// T = B*S = 1024 tokens. All inputs/outputs fp32.
#define NE 32
#define NK 4
#define NH 2048
#define NF 1024
#define NT 1024
#define NPAIR (NT * NK)

// Workspace layout (bytes)
static constexpr size_t OFF_CNT = 0;                         // int cnt[32]
static constexpr size_t OFF_ENT = 1024;                      // int entries[32][1024]
static constexpr size_t OFF_WTK = 1024 + 32 * 1024 * 4;      // float w_tk[4096]
static constexpr size_t OFF_ACT = 262144;                    // float act[4096][1024]
static constexpr size_t OFF_YP  = OFF_ACT + (size_t)NPAIR * NF * 4;  // float yp[4096][2048]
// total = OFF_YP + 4096*2048*4 = ~48.3 MB

// ---------------------------------------------------------------------------
// Kernel 1: router. One block per token. Computes 32 logits (fp32), writes
// raw logits to d_out tail, softmax + top-4, appends (t,k) to expert lists.
// ---------------------------------------------------------------------------
__global__ __launch_bounds__(256) void router_kernel(
    const float* __restrict__ x, const float* __restrict__ gate_w,
    float* __restrict__ logits_out, int* __restrict__ cnt,
    int* __restrict__ entries, float* __restrict__ w_tk) {
  __shared__ float xs[NH];
  __shared__ float logits_s[NE];
  const int t = blockIdx.x;
  const int tid = threadIdx.x;

  // stage x[t,:] into LDS (float4)
  for (int i = tid; i < NH / 4; i += 256) {
    *reinterpret_cast<float4*>(&xs[i * 4]) =
        *reinterpret_cast<const float4*>(&x[(size_t)t * NH + i * 4]);
  }
  __syncthreads();

  const int wave = tid >> 6, lane = tid & 63;
  // each wave computes 8 expert logits
  for (int ei = 0; ei < 8; ++ei) {
    const int e = wave * 8 + ei;
    const float* gw = gate_w + (size_t)e * NH;
    float s = 0.f;
    for (int h = lane; h < NH; h += 64) s += xs[h] * gw[h];
#pragma unroll
    for (int off = 32; off >= 1; off >>= 1) s += __shfl_xor(s, off, 64);
    if (lane == 0) logits_s[e] = s;
  }
  __syncthreads();

  if (wave == 0) {
    float v = (lane < NE) ? logits_s[lane] : -INFINITY;
    if (lane < NE) logits_out[(size_t)t * NE + lane] = v;
    // softmax (fp32)
    float m = v;
#pragma unroll
    for (int off = 32; off >= 1; off >>= 1) m = fmaxf(m, __shfl_xor(m, off, 64));
    float ex = (lane < NE) ? expf(v - m) : 0.f;
    float sum = ex;
#pragma unroll
    for (int off = 32; off >= 1; off >>= 1) sum += __shfl_xor(sum, off, 64);
    float pv = (lane < NE) ? (ex / sum) : -1.f;
    // top-4 (descending, ties -> lower index, matching lax.top_k)
    for (int k = 0; k < NK; ++k) {
      float bv = pv;
      int bi = lane;
#pragma unroll
      for (int off = 32; off >= 1; off >>= 1) {
        float ov = __shfl_xor(bv, off, 64);
        int oi = __shfl_xor(bi, off, 64);
        if (ov > bv || (ov == bv && oi < bi)) { bv = ov; bi = oi; }
      }
      if (lane == 0) {
        int pos = atomicAdd(&cnt[bi], 1);
        entries[bi * NT + pos] = t * NK + k;
        w_tk[t * NK + k] = bv;
      }
      if (lane == bi) pv = -1.f;  // remove winner
    }
  }
}

// ---------------------------------------------------------------------------
// Kernel 2: gate+up projection + SwiGLU for one expert's gathered tokens.
// Block tile: 64 rows (pairs) x 64 cols (f), K = 2048, BK = 32.
// grid = (F/64 = 16, maxRowTiles = 16, E = 32); 256 threads.
// ---------------------------------------------------------------------------
#define BK1 32
__global__ __launch_bounds__(256) void phase1_kernel(
    const float* __restrict__ x, const float* __restrict__ wg,
    const float* __restrict__ wu, const int* __restrict__ cnt,
    const int* __restrict__ entries, float* __restrict__ act) {
  const int e = blockIdx.z;
  const int n = cnt[e];
  const int rt = blockIdx.y;
  if (rt * 64 >= n) return;
  const int f0 = blockIdx.x * 64;

  __shared__ float Xs[64][36];       // [row][kk], padded stride 36
  __shared__ float Bg[BK1][64];
  __shared__ float Bu[BK1][64];
  __shared__ int pair_s[64];

  const int tid = threadIdx.x;
  if (tid < 64) {
    int idx = rt * 64 + tid;
    pair_s[tid] = (idx < n) ? entries[e * NT + idx] : -1;
  }
  __syncthreads();

  const int tx = tid & 15, ty = tid >> 4;
  float acc_g[4][4] = {{0}}, acc_u[4][4] = {{0}};
  const float* wge = wg + (size_t)e * NH * NF;
  const float* wue = wu + (size_t)e * NH * NF;

  for (int k0 = 0; k0 < NH; k0 += BK1) {
    // stage X: 64 rows x 32 k, float4 per thread-item
    for (int i = tid; i < 64 * (BK1 / 4); i += 256) {
      int row = i >> 3, kg = i & 7;
      int p = pair_s[row];
      float4 v = make_float4(0.f, 0.f, 0.f, 0.f);
      if (p >= 0) {
        int tok = p >> 2;
        v = *reinterpret_cast<const float4*>(&x[(size_t)tok * NH + k0 + kg * 4]);
      }
      *reinterpret_cast<float4*>(&Xs[row][kg * 4]) = v;
    }
    // stage Wg/Wu: 32 k x 64 f
    for (int i = tid; i < BK1 * 16; i += 256) {
      int kk = i >> 4, fg = i & 15;
      *reinterpret_cast<float4*>(&Bg[kk][fg * 4]) =
          *reinterpret_cast<const float4*>(&wge[(size_t)(k0 + kk) * NF + f0 + fg * 4]);
      *reinterpret_cast<float4*>(&Bu[kk][fg * 4]) =
          *reinterpret_cast<const float4*>(&wue[(size_t)(k0 + kk) * NF + f0 + fg * 4]);
    }
    __syncthreads();
#pragma unroll
    for (int kk = 0; kk < BK1; ++kk) {
      float a[4];
#pragma unroll
      for (int i = 0; i < 4; ++i) a[i] = Xs[ty * 4 + i][kk];
      float4 bg4 = *reinterpret_cast<float4*>(&Bg[kk][tx * 4]);
      float4 bu4 = *reinterpret_cast<float4*>(&Bu[kk][tx * 4]);
      float bg[4] = {bg4.x, bg4.y, bg4.z, bg4.w};
      float bu[4] = {bu4.x, bu4.y, bu4.z, bu4.w};
#pragma unroll
      for (int i = 0; i < 4; ++i)
#pragma unroll
        for (int j = 0; j < 4; ++j) {
          acc_g[i][j] += a[i] * bg[j];
          acc_u[i][j] += a[i] * bu[j];
        }
    }
    __syncthreads();
  }

  // epilogue: silu(g)*u -> act[pair][f]
#pragma unroll
  for (int i = 0; i < 4; ++i) {
    int p = pair_s[ty * 4 + i];
    if (p < 0) continue;
    float o[4];
#pragma unroll
    for (int j = 0; j < 4; ++j) {
      float g = acc_g[i][j];
      float sg = g / (1.f + expf(-g));
      o[j] = sg * acc_u[i][j];
    }
    *reinterpret_cast<float4*>(&act[(size_t)p * NF + f0 + tx * 4]) =
        make_float4(o[0], o[1], o[2], o[3]);
  }
}

// ---------------------------------------------------------------------------
// Kernel 3: down projection. Block tile: 64 rows (pairs) x 64 cols (h),
// K = 1024, BK = 32. grid = (H/64 = 32, 16, 32); 256 threads.
// Writes un-weighted per-pair y to yp[pair][h].
// ---------------------------------------------------------------------------
#define BK2 32
__global__ __launch_bounds__(256) void phase2_kernel(
    const float* __restrict__ act, const float* __restrict__ wd,
    const int* __restrict__ cnt, const int* __restrict__ entries,
    float* __restrict__ yp) {
  const int e = blockIdx.z;
  const int n = cnt[e];
  const int rt = blockIdx.y;
  if (rt * 64 >= n) return;
  const int h0 = blockIdx.x * 64;

  __shared__ float As[64][36];
  __shared__ float Bs[BK2][64];
  __shared__ int pair_s[64];

  const int tid = threadIdx.x;
  if (tid < 64) {
    int idx = rt * 64 + tid;
    pair_s[tid] = (idx < n) ? entries[e * NT + idx] : -1;
  }
  __syncthreads();

  const int tx = tid & 15, ty = tid >> 4;
  float acc[4][4] = {{0}};
  const float* wde = wd + (size_t)e * NF * NH;

  for (int k0 = 0; k0 < NF; k0 += BK2) {
    for (int i = tid; i < 64 * (BK2 / 4); i += 256) {
      int row = i >> 3, kg = i & 7;
      int p = pair_s[row];
      float4 v = make_float4(0.f, 0.f, 0.f, 0.f);
      if (p >= 0)
        v = *reinterpret_cast<const float4*>(&act[(size_t)p * NF + k0 + kg * 4]);
      *reinterpret_cast<float4*>(&As[row][kg * 4]) = v;
    }
    for (int i = tid; i < BK2 * 16; i += 256) {
      int kk = i >> 4, hg = i & 15;
      *reinterpret_cast<float4*>(&Bs[kk][hg * 4]) =
          *reinterpret_cast<const float4*>(&wde[(size_t)(k0 + kk) * NH + h0 + hg * 4]);
    }
    __syncthreads();
#pragma unroll
    for (int kk = 0; kk < BK2; ++kk) {
      float a[4];
#pragma unroll
      for (int i = 0; i < 4; ++i) a[i] = As[ty * 4 + i][kk];
      float4 b4 = *reinterpret_cast<float4*>(&Bs[kk][tx * 4]);
      float b[4] = {b4.x, b4.y, b4.z, b4.w};
#pragma unroll
      for (int i = 0; i < 4; ++i)
#pragma unroll
        for (int j = 0; j < 4; ++j) acc[i][j] += a[i] * b[j];
    }
    __syncthreads();
  }

#pragma unroll
  for (int i = 0; i < 4; ++i) {
    int p = pair_s[ty * 4 + i];
    if (p < 0) continue;
    *reinterpret_cast<float4*>(&yp[(size_t)p * NH + h0 + tx * 4]) =
        make_float4(acc[i][0], acc[i][1], acc[i][2], acc[i][3]);
  }
}

// ---------------------------------------------------------------------------
// Kernel 4: combine. out[t,h] = sum_k w_tk[t*4+k] * yp[t*4+k][h].
// Deterministic (no atomics).
// ---------------------------------------------------------------------------
__global__ __launch_bounds__(256) void combine_kernel(
    const float* __restrict__ yp, const float* __restrict__ w_tk,
    float* __restrict__ out) {
  const size_t idx = (size_t)blockIdx.x * 256 + threadIdx.x;  // < NT*NH
  const int t = (int)(idx >> 11);
  const int h = (int)(idx & (NH - 1));
  float s = 0.f;
#pragma unroll
  for (int k = 0; k < NK; ++k)
    s += w_tk[t * NK + k] * yp[((size_t)(t * NK + k)) * NH + h];
  out[idx] = s;
}

// ---------------------------------------------------------------------------
extern "C" void kernel_launch(void* const* d_in, const int* in_sizes, int n_in,
                              void* d_out, int out_size, void* d_ws,
                              size_t ws_size, hipStream_t stream) {
  const float* x      = (const float*)d_in[0];  // [2,512,2048]
  const float* gate_w = (const float*)d_in[1];  // [32,2048]
  const float* wg     = (const float*)d_in[2];  // [32,2048,1024]
  const float* wu     = (const float*)d_in[3];  // [32,2048,1024]
  const float* wd     = (const float*)d_in[4];  // [32,1024,2048]

  float* out        = (float*)d_out;                    // [T*H] = 2,097,152
  float* logits_out = (float*)d_out + (size_t)NT * NH;  // [T*E] = 32,768

  char* ws = (char*)d_ws;
  int* cnt      = (int*)(ws + OFF_CNT);
  int* entries  = (int*)(ws + OFF_ENT);
  float* w_tk   = (float*)(ws + OFF_WTK);
  float* act    = (float*)(ws + OFF_ACT);
  float* yp     = (float*)(ws + OFF_YP);

  hipMemsetAsync(ws, 0, 1024, stream);  // zero expert counters

  router_kernel<<<NT, 256, 0, stream>>>(x, gate_w, logits_out, cnt, entries, w_tk);
  phase1_kernel<<<dim3(NF / 64, 16, NE), 256, 0, stream>>>(x, wg, wu, cnt, entries, act);
  phase2_kernel<<<dim3(NH / 64, 16, NE), 256, 0, stream>>>(act, wd, cnt, entries, yp);
  combine_kernel<<<(NT * NH) / 256, 256, 0, stream>>>(yp, w_tk, out);
}

// Round 2
// 526.587 us; speedup vs baseline: 1.9679x; 1.9679x over previous
//
#include <hip/hip_runtime.h>
#include <hip/hip_bf16.h>
#include <math.h>

// OLMoE sparse MoE block: E=32, K=4, H=2048, F=1024, T=1024 tokens.
#define NE 32
#define NK 4
#define NH 2048
#define NF 1024
#define NT 1024
#define NPAIR (NT * NK)

// MFMA GEMM tiles
#define BM 128
#define BN 64
#define BK 64

typedef __attribute__((ext_vector_type(8))) short short8;
typedef __attribute__((ext_vector_type(4))) float f32x4;

// Workspace layout (bytes)
static constexpr size_t OFF_CNT = 0;                             // int cnt[32]
static constexpr size_t OFF_ENT = 1024;                          // int entries[32][1024]
static constexpr size_t OFF_WTK = 1024 + 32 * 1024 * 4;          // float w_tk[4096]
static constexpr size_t OFF_ACT = 262144;                        // bf16 act[4096][1024]
static constexpr size_t OFF_YP  = OFF_ACT + (size_t)NPAIR * NF * 2;  // float yp[4096][2048]
// total = OFF_YP + 4096*2048*4 ≈ 42 MB

// ---------------------------------------------------------------------------
// helpers
// ---------------------------------------------------------------------------
__device__ inline unsigned bfbits(float f) {
  return (unsigned)__builtin_bit_cast(unsigned short, __float2bfloat16(f));
}
__device__ inline unsigned pkbf(float lo, float hi) {
  return bfbits(lo) | (bfbits(hi) << 16);
}
// XOR-swizzled element index for a [rows][64] bf16 LDS tile (row stride 128 B).
// byte = r*128 + k*2, then byte ^= (r&7)<<4 — spreads a 16-lane column read
// across 8 distinct 16B slots (2-way residual = free, m136).
__device__ inline int swz(int r, int k) {
  int b = (r << 7) | (k << 1);
  return (b ^ ((r & 7) << 4)) >> 1;
}

// ---------------------------------------------------------------------------
// Kernel 1: router. One block per token: 32 logits -> softmax -> top-4,
// append (t*4+k) to expert lists, store weight.
// ---------------------------------------------------------------------------
__global__ __launch_bounds__(256) void router_kernel(
    const float* __restrict__ x, const float* __restrict__ gate_w,
    float* __restrict__ logits_out, int* __restrict__ cnt,
    int* __restrict__ entries, float* __restrict__ w_tk) {
  __shared__ float xs[NH];
  __shared__ float logits_s[NE];
  const int t = blockIdx.x;
  const int tid = threadIdx.x;

  for (int i = tid; i < NH / 4; i += 256) {
    *reinterpret_cast<float4*>(&xs[i * 4]) =
        *reinterpret_cast<const float4*>(&x[(size_t)t * NH + i * 4]);
  }
  __syncthreads();

  const int wave = tid >> 6, lane = tid & 63;
  for (int ei = 0; ei < 8; ++ei) {
    const int e = wave * 8 + ei;
    const float* gw = gate_w + (size_t)e * NH;
    float s = 0.f;
    for (int h = lane; h < NH; h += 64) s += xs[h] * gw[h];
#pragma unroll
    for (int off = 32; off >= 1; off >>= 1) s += __shfl_xor(s, off, 64);
    if (lane == 0) logits_s[e] = s;
  }
  __syncthreads();

  if (wave == 0) {
    float v = (lane < NE) ? logits_s[lane] : -INFINITY;
    if (lane < NE) logits_out[(size_t)t * NE + lane] = v;
    float m = v;
#pragma unroll
    for (int off = 32; off >= 1; off >>= 1) m = fmaxf(m, __shfl_xor(m, off, 64));
    float ex = (lane < NE) ? expf(v - m) : 0.f;
    float sum = ex;
#pragma unroll
    for (int off = 32; off >= 1; off >>= 1) sum += __shfl_xor(sum, off, 64);
    float pv = (lane < NE) ? (ex / sum) : -1.f;
    for (int k = 0; k < NK; ++k) {
      float bv = pv;
      int bi = lane;
#pragma unroll
      for (int off = 32; off >= 1; off >>= 1) {
        float ov = __shfl_xor(bv, off, 64);
        int oi = __shfl_xor(bi, off, 64);
        if (ov > bv || (ov == bv && oi < bi)) { bv = ov; bi = oi; }
      }
      if (lane == 0) {
        int pos = atomicAdd(&cnt[bi], 1);
        entries[bi * NT + pos] = t * NK + k;
        w_tk[t * NK + k] = bv;
      }
      if (lane == bi) pv = -1.f;
    }
  }
}

// ---------------------------------------------------------------------------
// Kernel 2: gate+up MFMA GEMM + SwiGLU. Tile 128(pairs) x 64(f), K=2048.
// grid = (NF/64=16, 8 rowtiles, 32 experts), 256 threads = 4 waves (2x2).
// fp32 HBM -> bf16 LDS (fused convert), mfma_f32_16x16x32_bf16.
// ---------------------------------------------------------------------------
__global__ __launch_bounds__(256) void phase1_mfma(
    const float* __restrict__ x, const float* __restrict__ wg,
    const float* __restrict__ wu, const int* __restrict__ cnt,
    const int* __restrict__ entries, unsigned short* __restrict__ act) {
  const int e = blockIdx.z;
  const int n_e = cnt[e];
  const int rt = blockIdx.y;
  if (rt * BM >= n_e) return;
  const int f0 = blockIdx.x * BN;

  __shared__ unsigned short As[BM * BK];   // [m][k] swizzled, 16 KB
  __shared__ unsigned short Bgs[BN * BK];  // [n][k] swizzled, 8 KB
  __shared__ unsigned short Bus[BN * BK];  // 8 KB
  __shared__ int pair_s[BM];

  const int tid = threadIdx.x;
  if (tid < BM) {
    int idx = rt * BM + tid;
    pair_s[tid] = (idx < n_e) ? entries[e * NT + idx] : -1;
  }
  __syncthreads();

  const int lane = tid & 63, wid = tid >> 6;
  const int wm = (wid >> 1) * 64, wn = (wid & 1) * 32;
  const int lm = lane & 15, lk = (lane >> 4) * 8;

  f32x4 accg[4][2], accu[4][2];
#pragma unroll
  for (int i = 0; i < 4; ++i)
#pragma unroll
    for (int j = 0; j < 2; ++j) {
      accg[i][j] = (f32x4)(0.f);
      accu[i][j] = (f32x4)(0.f);
    }

  // staging roles
  const int ar = tid >> 1, akh = (tid & 1) * 32;      // A: row, k-half
  const int pa = pair_s[ar];
  const float* arow = (pa >= 0) ? x + (size_t)(pa >> 2) * NH + akh : x;
  const int bn = tid & 63, bq = tid >> 6;             // B: col n, k-quarter
  const float* wge = wg + (size_t)e * NH * NF + f0 + bn;
  const float* wue = wu + (size_t)e * NH * NF + f0 + bn;

  for (int k0 = 0; k0 < NH; k0 += BK) {
    // A stage: 128 x 64 fp32 -> bf16
#pragma unroll
    for (int g = 0; g < 8; ++g) {
      float4 v = make_float4(0.f, 0.f, 0.f, 0.f);
      if (pa >= 0) v = *reinterpret_cast<const float4*>(arow + k0 + 4 * g);
      uint2 u;
      u.x = pkbf(v.x, v.y);
      u.y = pkbf(v.z, v.w);
      *reinterpret_cast<uint2*>(&As[swz(ar, akh + 4 * g)]) = u;
    }
    // B stage: 64k x 64n fp32 -> bf16, k-packed into [n][k]
#pragma unroll
    for (int g = 0; g < 4; ++g) {
      const int k4 = bq * 16 + 4 * g;
      const float* pg = wge + (size_t)(k0 + k4) * NF;
      uint2 u;
      u.x = pkbf(pg[0], pg[NF]);
      u.y = pkbf(pg[2 * NF], pg[3 * NF]);
      *reinterpret_cast<uint2*>(&Bgs[swz(bn, k4)]) = u;
      const float* pu = wue + (size_t)(k0 + k4) * NF;
      uint2 w;
      w.x = pkbf(pu[0], pu[NF]);
      w.y = pkbf(pu[2 * NF], pu[3 * NF]);
      *reinterpret_cast<uint2*>(&Bus[swz(bn, k4)]) = w;
    }
    __syncthreads();
#pragma unroll
    for (int kc = 0; kc < 2; ++kc) {
      short8 a[4], bg[2], bu[2];
#pragma unroll
      for (int mf = 0; mf < 4; ++mf)
        a[mf] = *reinterpret_cast<const short8*>(&As[swz(wm + mf * 16 + lm, kc * 32 + lk)]);
#pragma unroll
      for (int nf = 0; nf < 2; ++nf) {
        bg[nf] = *reinterpret_cast<const short8*>(&Bgs[swz(wn + nf * 16 + lm, kc * 32 + lk)]);
        bu[nf] = *reinterpret_cast<const short8*>(&Bus[swz(wn + nf * 16 + lm, kc * 32 + lk)]);
      }
#pragma unroll
      for (int mf = 0; mf < 4; ++mf)
#pragma unroll
        for (int nf = 0; nf < 2; ++nf) {
          accg[mf][nf] = __builtin_amdgcn_mfma_f32_16x16x32_bf16(a[mf], bg[nf], accg[mf][nf], 0, 0, 0);
          accu[mf][nf] = __builtin_amdgcn_mfma_f32_16x16x32_bf16(a[mf], bu[nf], accu[mf][nf], 0, 0, 0);
        }
    }
    __syncthreads();
  }

  // epilogue: silu(g)*u -> act bf16. D layout: col=lane&15, row=(lane>>4)*4+r.
  const int rbase = wm + (lane >> 4) * 4;
#pragma unroll
  for (int mf = 0; mf < 4; ++mf) {
#pragma unroll
    for (int r = 0; r < 4; ++r) {
      const int row = rbase + mf * 16 + r;
      const int p = pair_s[row];
      if (p < 0) continue;
#pragma unroll
      for (int nf = 0; nf < 2; ++nf) {
        float g = accg[mf][nf][r], u = accu[mf][nf][r];
        float o = (g / (1.f + __expf(-g))) * u;
        act[(size_t)p * NF + f0 + wn + nf * 16 + lm] = (unsigned short)bfbits(o);
      }
    }
  }
}

// ---------------------------------------------------------------------------
// Kernel 3: down-proj MFMA GEMM. Tile 128(pairs) x 64(h), K=F=1024.
// grid = (NH/64=32, 8, 32). A = act (bf16, direct), B = w_down fp32->bf16.
// ---------------------------------------------------------------------------
__global__ __launch_bounds__(256) void phase2_mfma(
    const unsigned short* __restrict__ act, const float* __restrict__ wd,
    const int* __restrict__ cnt, const int* __restrict__ entries,
    float* __restrict__ yp) {
  const int e = blockIdx.z;
  const int n_e = cnt[e];
  const int rt = blockIdx.y;
  if (rt * BM >= n_e) return;
  const int h0 = blockIdx.x * BN;

  __shared__ unsigned short As[BM * BK];  // 16 KB
  __shared__ unsigned short Bs[BN * BK];  // 8 KB
  __shared__ int pair_s[BM];

  const int tid = threadIdx.x;
  if (tid < BM) {
    int idx = rt * BM + tid;
    pair_s[tid] = (idx < n_e) ? entries[e * NT + idx] : -1;
  }
  __syncthreads();

  const int lane = tid & 63, wid = tid >> 6;
  const int wm = (wid >> 1) * 64, wn = (wid & 1) * 32;
  const int lm = lane & 15, lk = (lane >> 4) * 8;

  f32x4 acc[4][2];
#pragma unroll
  for (int i = 0; i < 4; ++i)
#pragma unroll
    for (int j = 0; j < 2; ++j) acc[i][j] = (f32x4)(0.f);

  const int ar = tid >> 1, akh = (tid & 1) * 32;
  const int pa = pair_s[ar];
  const unsigned short* arow = (pa >= 0) ? act + (size_t)pa * NF + akh : act;
  const int bn = tid & 63, bq = tid >> 6;
  const float* wde = wd + (size_t)e * NF * NH + h0 + bn;

  for (int k0 = 0; k0 < NF; k0 += BK) {
    // A stage: bf16 direct copy, 4 x 16B per thread
#pragma unroll
    for (int g = 0; g < 4; ++g) {
      short8 v = (short8)(short)0;
      if (pa >= 0) v = *reinterpret_cast<const short8*>(arow + k0 + 8 * g);
      *reinterpret_cast<short8*>(&As[swz(ar, akh + 8 * g)]) = v;
    }
    // B stage: fp32 -> bf16 k-packed
#pragma unroll
    for (int g = 0; g < 4; ++g) {
      const int k4 = bq * 16 + 4 * g;
      const float* pb = wde + (size_t)(k0 + k4) * NH;
      uint2 u;
      u.x = pkbf(pb[0], pb[NH]);
      u.y = pkbf(pb[2 * NH], pb[3 * NH]);
      *reinterpret_cast<uint2*>(&Bs[swz(bn, k4)]) = u;
    }
    __syncthreads();
#pragma unroll
    for (int kc = 0; kc < 2; ++kc) {
      short8 a[4], b[2];
#pragma unroll
      for (int mf = 0; mf < 4; ++mf)
        a[mf] = *reinterpret_cast<const short8*>(&As[swz(wm + mf * 16 + lm, kc * 32 + lk)]);
#pragma unroll
      for (int nf = 0; nf < 2; ++nf)
        b[nf] = *reinterpret_cast<const short8*>(&Bs[swz(wn + nf * 16 + lm, kc * 32 + lk)]);
#pragma unroll
      for (int mf = 0; mf < 4; ++mf)
#pragma unroll
        for (int nf = 0; nf < 2; ++nf)
          acc[mf][nf] = __builtin_amdgcn_mfma_f32_16x16x32_bf16(a[mf], b[nf], acc[mf][nf], 0, 0, 0);
    }
    __syncthreads();
  }

  const int rbase = wm + (lane >> 4) * 4;
#pragma unroll
  for (int mf = 0; mf < 4; ++mf) {
#pragma unroll
    for (int r = 0; r < 4; ++r) {
      const int row = rbase + mf * 16 + r;
      const int p = pair_s[row];
      if (p < 0) continue;
#pragma unroll
      for (int nf = 0; nf < 2; ++nf)
        yp[(size_t)p * NH + h0 + wn + nf * 16 + lm] = acc[mf][nf][r];
    }
  }
}

// ---------------------------------------------------------------------------
// Kernel 4: combine. out[t,h] = sum_k w_tk[t*4+k] * yp[t*4+k][h]. Deterministic.
// ---------------------------------------------------------------------------
__global__ __launch_bounds__(256) void combine_kernel(
    const float* __restrict__ yp, const float* __restrict__ w_tk,
    float* __restrict__ out) {
  const size_t idx = (size_t)blockIdx.x * 256 + threadIdx.x;
  const int t = (int)(idx >> 11);
  const int h = (int)(idx & (NH - 1));
  float s = 0.f;
#pragma unroll
  for (int k = 0; k < NK; ++k)
    s += w_tk[t * NK + k] * yp[((size_t)(t * NK + k)) * NH + h];
  out[idx] = s;
}

// ---------------------------------------------------------------------------
extern "C" void kernel_launch(void* const* d_in, const int* in_sizes, int n_in,
                              void* d_out, int out_size, void* d_ws,
                              size_t ws_size, hipStream_t stream) {
  const float* x      = (const float*)d_in[0];
  const float* gate_w = (const float*)d_in[1];
  const float* wg     = (const float*)d_in[2];
  const float* wu     = (const float*)d_in[3];
  const float* wd     = (const float*)d_in[4];

  float* out        = (float*)d_out;
  float* logits_out = (float*)d_out + (size_t)NT * NH;

  char* ws = (char*)d_ws;
  int* cnt             = (int*)(ws + OFF_CNT);
  int* entries         = (int*)(ws + OFF_ENT);
  float* w_tk          = (float*)(ws + OFF_WTK);
  unsigned short* act  = (unsigned short*)(ws + OFF_ACT);
  float* yp            = (float*)(ws + OFF_YP);

  hipMemsetAsync(ws, 0, 1024, stream);  // zero expert counters

  router_kernel<<<NT, 256, 0, stream>>>(x, gate_w, logits_out, cnt, entries, w_tk);
  phase1_mfma<<<dim3(NF / BN, 8, NE), 256, 0, stream>>>(x, wg, wu, cnt, entries, act);
  phase2_mfma<<<dim3(NH / BN, 8, NE), 256, 0, stream>>>(act, wd, cnt, entries, yp);
  combine_kernel<<<(NT * NH) / 256, 256, 0, stream>>>(yp, w_tk, out);
}

// Round 3
// 389.609 us; speedup vs baseline: 2.6598x; 1.3516x over previous
//
#include <hip/hip_runtime.h>
#include <hip/hip_bf16.h>
#include <math.h>

// OLMoE sparse MoE block: E=32, K=4, H=2048, F=1024, T=1024 tokens.
#define NE 32
#define NK 4
#define NH 2048
#define NF 1024
#define NT 1024

#define BM 128
#define BN 64
#define BK 64

typedef __attribute__((ext_vector_type(8))) short short8;
typedef __attribute__((ext_vector_type(4))) float f32x4;

// Workspace layout (bytes); total ~46 MB (round-1 used 50.8 MB OK)
static constexpr size_t OFF_CNT = 0;                               // int cnt[32]
static constexpr size_t OFF_ENT = 1024;                            // int entries[32][1024]
static constexpr size_t OFF_WTK = 1024 + 32 * 1024 * 4;            // float w_tk[4096]
static constexpr size_t OFF_XB  = 262144;                          // bf16 xb[1024][2048] (4 MB)
static constexpr size_t OFF_ACT = OFF_XB + (size_t)NT * NH * 2;    // bf16 act[4096][1024] (8 MB)
static constexpr size_t OFF_YP  = OFF_ACT + (size_t)NT * NK * NF * 2;  // f32 yp[4096][2048] (32 MB)

// ---------------------------------------------------------------------------
__device__ inline unsigned bfbits(float f) {
  return (unsigned)__builtin_bit_cast(unsigned short, __float2bfloat16(f));
}
__device__ inline unsigned pkbf(float lo, float hi) {
  return bfbits(lo) | (bfbits(hi) << 16);
}
// XOR-swizzled element index for a [rows][64] bf16 tile (row stride 128 B):
// byte = r*128 + k*2, byte ^= (r&7)<<4. Involution, 16B-block preserving.
__device__ inline int swz(int r, int k) {
  int b = (r << 7) | (k << 1);
  return (b ^ ((r & 7) << 4)) >> 1;
}
// async global->LDS 16B: per-lane global src, wave-uniform LDS base + lane*16
__device__ inline void gload16(const unsigned short* g, void* l) {
  __builtin_amdgcn_global_load_lds(
      (const __attribute__((address_space(1))) unsigned int*)g,
      (__attribute__((address_space(3))) unsigned int*)l, 16, 0, 0);
}

// ---------------------------------------------------------------------------
// Kernel 1: router. One block per token: 32 logits -> softmax -> top-4,
// append to expert lists; also emit bf16 copy of x into ws (xb).
// ---------------------------------------------------------------------------
__global__ __launch_bounds__(256) void router_kernel(
    const float* __restrict__ x, const float* __restrict__ gate_w,
    float* __restrict__ logits_out, int* __restrict__ cnt,
    int* __restrict__ entries, float* __restrict__ w_tk,
    unsigned short* __restrict__ xb) {
  __shared__ float xs[NH];
  __shared__ float logits_s[NE];
  const int t = blockIdx.x;
  const int tid = threadIdx.x;

  for (int i = tid; i < NH / 4; i += 256) {
    *reinterpret_cast<float4*>(&xs[i * 4]) =
        *reinterpret_cast<const float4*>(&x[(size_t)t * NH + i * 4]);
  }
  __syncthreads();

  // bf16 copy of this token's row (each thread packs 8 elements)
  {
    unsigned u[4];
#pragma unroll
    for (int j = 0; j < 4; ++j)
      u[j] = pkbf(xs[tid * 8 + 2 * j], xs[tid * 8 + 2 * j + 1]);
    *reinterpret_cast<uint4*>(&xb[(size_t)t * NH + tid * 8]) =
        make_uint4(u[0], u[1], u[2], u[3]);
  }

  const int wave = tid >> 6, lane = tid & 63;
  for (int ei = 0; ei < 8; ++ei) {
    const int e = wave * 8 + ei;
    const float* gw = gate_w + (size_t)e * NH;
    float s = 0.f;
    for (int h = lane; h < NH; h += 64) s += xs[h] * gw[h];
#pragma unroll
    for (int off = 32; off >= 1; off >>= 1) s += __shfl_xor(s, off, 64);
    if (lane == 0) logits_s[e] = s;
  }
  __syncthreads();

  if (wave == 0) {
    float v = (lane < NE) ? logits_s[lane] : -INFINITY;
    if (lane < NE) logits_out[(size_t)t * NE + lane] = v;
    float m = v;
#pragma unroll
    for (int off = 32; off >= 1; off >>= 1) m = fmaxf(m, __shfl_xor(m, off, 64));
    float ex = (lane < NE) ? expf(v - m) : 0.f;
    float sum = ex;
#pragma unroll
    for (int off = 32; off >= 1; off >>= 1) sum += __shfl_xor(sum, off, 64);
    float pv = (lane < NE) ? (ex / sum) : -1.f;
    for (int k = 0; k < NK; ++k) {
      float bv = pv;
      int bi = lane;
#pragma unroll
      for (int off = 32; off >= 1; off >>= 1) {
        float ov = __shfl_xor(bv, off, 64);
        int oi = __shfl_xor(bi, off, 64);
        if (ov > bv || (ov == bv && oi < bi)) { bv = ov; bi = oi; }
      }
      if (lane == 0) {
        int pos = atomicAdd(&cnt[bi], 1);
        entries[bi * NT + pos] = t * NK + k;
        w_tk[t * NK + k] = bv;
      }
      if (lane == bi) pv = -1.f;
    }
  }
}

// ---------------------------------------------------------------------------
// Kernel 2: gate+up MFMA GEMM + SwiGLU, double-buffered pipeline.
// Tile 128(pairs) x 64(f), K=2048, BK=64. 4 waves.
// A: bf16 xb via global_load_lds (inverse-swizzled per-lane source).
// B: fp32 strided loads -> reg -> cvt -> swizzled LDS (issued before compute).
// ---------------------------------------------------------------------------
__global__ __launch_bounds__(256) void phase1_mfma(
    const unsigned short* __restrict__ xb, const float* __restrict__ wg,
    const float* __restrict__ wu, const int* __restrict__ cnt,
    const int* __restrict__ entries, unsigned short* __restrict__ act) {
  const int e = blockIdx.z;
  const int n_e = cnt[e];
  const int rt = blockIdx.y;
  if (rt * BM >= n_e) return;
  const int f0 = blockIdx.x * BN;

  __shared__ unsigned short As[2][BM * BK];   // 2 x 16 KB
  __shared__ unsigned short Bgs[2][BN * BK];  // 2 x 8 KB
  __shared__ unsigned short Bus[2][BN * BK];  // 2 x 8 KB
  __shared__ int pair_s[BM];

  const int tid = threadIdx.x;
  if (tid < BM) {
    int idx = rt * BM + tid;
    pair_s[tid] = (idx < n_e) ? entries[e * NT + idx] : -1;
  }
  __syncthreads();

  const int lane = tid & 63, wid = tid >> 6;

  // A gload_lds sources: wave wid stages rows [wid*32, wid*32+32).
  // LDS bytes (linear): wid*4096 + j*1024 + lane*16 -> row = wid*32+j*8+(lane>>3),
  // swizzle-inverse k = ((lane&7)^(lane>>3))*8.
  const int klane = ((lane & 7) ^ (lane >> 3)) * 8;
  const unsigned short* asrc[4];
#pragma unroll
  for (int j = 0; j < 4; ++j) {
    int row = wid * 32 + j * 8 + (lane >> 3);
    int p = pair_s[row];
    int tok = (p >= 0) ? (p >> 2) : 0;
    asrc[j] = xb + (size_t)tok * NH + klane;
  }

  // B staging roles: lane = n column, wid = k-quarter (16 k each)
  const int bn = lane, bq = wid;
  const float* bgb = wg + (size_t)e * NH * NF + f0 + bn;
  const float* bub = wu + (size_t)e * NH * NF + f0 + bn;
  float rg[16], ru[16];

  const int wm = (wid >> 1) * 64, wn = (wid & 1) * 32;
  const int lm = lane & 15, lk = (lane >> 4) * 8;

  f32x4 accg[4][2], accu[4][2];
#pragma unroll
  for (int i = 0; i < 4; ++i)
#pragma unroll
    for (int j = 0; j < 2; ++j) {
      accg[i][j] = (f32x4)(0.f);
      accu[i][j] = (f32x4)(0.f);
    }

  auto issueA = [&](int k0, int b) {
#pragma unroll
    for (int j = 0; j < 4; ++j)
      gload16(asrc[j] + k0, (char*)&As[b][0] + wid * 4096 + j * 1024);
  };
  auto loadB = [&](int k0) {
    const int kb = k0 + bq * 16;
#pragma unroll
    for (int g = 0; g < 4; ++g)
#pragma unroll
      for (int i = 0; i < 4; ++i) {
        rg[g * 4 + i] = bgb[(size_t)(kb + g * 4 + i) * NF];
        ru[g * 4 + i] = bub[(size_t)(kb + g * 4 + i) * NF];
      }
  };
  auto storeB = [&](int b) {
    const int kb = bq * 16;
#pragma unroll
    for (int g = 0; g < 4; ++g) {
      uint2 ug, uu;
      ug.x = pkbf(rg[g * 4 + 0], rg[g * 4 + 1]);
      ug.y = pkbf(rg[g * 4 + 2], rg[g * 4 + 3]);
      uu.x = pkbf(ru[g * 4 + 0], ru[g * 4 + 1]);
      uu.y = pkbf(ru[g * 4 + 2], ru[g * 4 + 3]);
      *reinterpret_cast<uint2*>(&Bgs[b][swz(bn, kb + g * 4)]) = ug;
      *reinterpret_cast<uint2*>(&Bus[b][swz(bn, kb + g * 4)]) = uu;
    }
  };

  // prologue: stage tile 0
  issueA(0, 0);
  loadB(0);
  storeB(0);
  __syncthreads();  // drains gloads (compiler vmcnt0) + B writes visible

  const int NS = NH / BK;  // 32
  for (int t = 0; t < NS; ++t) {
    const int c = t & 1;
    if (t + 1 < NS) {
      issueA((t + 1) * BK, c ^ 1);  // async, in flight across compute
      loadB((t + 1) * BK);          // into regs, in flight across compute
    }
#pragma unroll
    for (int kc = 0; kc < 2; ++kc) {
      short8 a[4], bg[2], bu[2];
#pragma unroll
      for (int mf = 0; mf < 4; ++mf)
        a[mf] = *reinterpret_cast<const short8*>(
            &As[c][swz(wm + mf * 16 + lm, kc * 32 + lk)]);
#pragma unroll
      for (int nf = 0; nf < 2; ++nf) {
        bg[nf] = *reinterpret_cast<const short8*>(
            &Bgs[c][swz(wn + nf * 16 + lm, kc * 32 + lk)]);
        bu[nf] = *reinterpret_cast<const short8*>(
            &Bus[c][swz(wn + nf * 16 + lm, kc * 32 + lk)]);
      }
#pragma unroll
      for (int mf = 0; mf < 4; ++mf)
#pragma unroll
        for (int nf = 0; nf < 2; ++nf) {
          accg[mf][nf] = __builtin_amdgcn_mfma_f32_16x16x32_bf16(a[mf], bg[nf], accg[mf][nf], 0, 0, 0);
          accu[mf][nf] = __builtin_amdgcn_mfma_f32_16x16x32_bf16(a[mf], bu[nf], accu[mf][nf], 0, 0, 0);
        }
    }
    __syncthreads();                    // #1: done reading buf c
    if (t + 1 < NS) storeB(c ^ 1);      // cvt + LDS write next B
    __syncthreads();                    // #2: buf c^1 staged
  }

  // epilogue: silu(g)*u -> act bf16. D layout: col=lane&15, row=(lane>>4)*4+r.
  const int rbase = wm + (lane >> 4) * 4;
#pragma unroll
  for (int mf = 0; mf < 4; ++mf) {
#pragma unroll
    for (int r = 0; r < 4; ++r) {
      const int row = rbase + mf * 16 + r;
      const int p = pair_s[row];
      if (p < 0) continue;
#pragma unroll
      for (int nf = 0; nf < 2; ++nf) {
        float g = accg[mf][nf][r], u = accu[mf][nf][r];
        float o = (g / (1.f + __expf(-g))) * u;
        act[(size_t)p * NF + f0 + wn + nf * 16 + lm] = (unsigned short)bfbits(o);
      }
    }
  }
}

// ---------------------------------------------------------------------------
// Kernel 3: down-proj MFMA GEMM, same pipeline. Tile 128 x 64, K=F=1024.
// ---------------------------------------------------------------------------
__global__ __launch_bounds__(256) void phase2_mfma(
    const unsigned short* __restrict__ act, const float* __restrict__ wd,
    const int* __restrict__ cnt, const int* __restrict__ entries,
    float* __restrict__ yp) {
  const int e = blockIdx.z;
  const int n_e = cnt[e];
  const int rt = blockIdx.y;
  if (rt * BM >= n_e) return;
  const int h0 = blockIdx.x * BN;

  __shared__ unsigned short As[2][BM * BK];  // 2 x 16 KB
  __shared__ unsigned short Bs[2][BN * BK];  // 2 x 8 KB
  __shared__ int pair_s[BM];

  const int tid = threadIdx.x;
  if (tid < BM) {
    int idx = rt * BM + tid;
    pair_s[tid] = (idx < n_e) ? entries[e * NT + idx] : -1;
  }
  __syncthreads();

  const int lane = tid & 63, wid = tid >> 6;

  const int klane = ((lane & 7) ^ (lane >> 3)) * 8;
  const unsigned short* asrc[4];
#pragma unroll
  for (int j = 0; j < 4; ++j) {
    int row = wid * 32 + j * 8 + (lane >> 3);
    int p = pair_s[row];
    int pa = (p >= 0) ? p : 0;
    asrc[j] = act + (size_t)pa * NF + klane;
  }

  const int bn = lane, bq = wid;
  const float* bb = wd + (size_t)e * NF * NH + h0 + bn;
  float rb[16];

  const int wm = (wid >> 1) * 64, wn = (wid & 1) * 32;
  const int lm = lane & 15, lk = (lane >> 4) * 8;

  f32x4 acc[4][2];
#pragma unroll
  for (int i = 0; i < 4; ++i)
#pragma unroll
    for (int j = 0; j < 2; ++j) acc[i][j] = (f32x4)(0.f);

  auto issueA = [&](int k0, int b) {
#pragma unroll
    for (int j = 0; j < 4; ++j)
      gload16(asrc[j] + k0, (char*)&As[b][0] + wid * 4096 + j * 1024);
  };
  auto loadB = [&](int k0) {
    const int kb = k0 + bq * 16;
#pragma unroll
    for (int g = 0; g < 4; ++g)
#pragma unroll
      for (int i = 0; i < 4; ++i)
        rb[g * 4 + i] = bb[(size_t)(kb + g * 4 + i) * NH];
  };
  auto storeB = [&](int b) {
    const int kb = bq * 16;
#pragma unroll
    for (int g = 0; g < 4; ++g) {
      uint2 u;
      u.x = pkbf(rb[g * 4 + 0], rb[g * 4 + 1]);
      u.y = pkbf(rb[g * 4 + 2], rb[g * 4 + 3]);
      *reinterpret_cast<uint2*>(&Bs[b][swz(bn, kb + g * 4)]) = u;
    }
  };

  issueA(0, 0);
  loadB(0);
  storeB(0);
  __syncthreads();

  const int NS = NF / BK;  // 16
  for (int t = 0; t < NS; ++t) {
    const int c = t & 1;
    if (t + 1 < NS) {
      issueA((t + 1) * BK, c ^ 1);
      loadB((t + 1) * BK);
    }
#pragma unroll
    for (int kc = 0; kc < 2; ++kc) {
      short8 a[4], b2[2];
#pragma unroll
      for (int mf = 0; mf < 4; ++mf)
        a[mf] = *reinterpret_cast<const short8*>(
            &As[c][swz(wm + mf * 16 + lm, kc * 32 + lk)]);
#pragma unroll
      for (int nf = 0; nf < 2; ++nf)
        b2[nf] = *reinterpret_cast<const short8*>(
            &Bs[c][swz(wn + nf * 16 + lm, kc * 32 + lk)]);
#pragma unroll
      for (int mf = 0; mf < 4; ++mf)
#pragma unroll
        for (int nf = 0; nf < 2; ++nf)
          acc[mf][nf] = __builtin_amdgcn_mfma_f32_16x16x32_bf16(a[mf], b2[nf], acc[mf][nf], 0, 0, 0);
    }
    __syncthreads();
    if (t + 1 < NS) storeB(c ^ 1);
    __syncthreads();
  }

  const int rbase = wm + (lane >> 4) * 4;
#pragma unroll
  for (int mf = 0; mf < 4; ++mf) {
#pragma unroll
    for (int r = 0; r < 4; ++r) {
      const int row = rbase + mf * 16 + r;
      const int p = pair_s[row];
      if (p < 0) continue;
#pragma unroll
      for (int nf = 0; nf < 2; ++nf)
        yp[(size_t)p * NH + h0 + wn + nf * 16 + lm] = acc[mf][nf][r];
    }
  }
}

// ---------------------------------------------------------------------------
// Kernel 4: combine. out[t,h] = sum_k w_tk[t*4+k] * yp[t*4+k][h]. Deterministic.
// ---------------------------------------------------------------------------
__global__ __launch_bounds__(256) void combine_kernel(
    const float* __restrict__ yp, const float* __restrict__ w_tk,
    float* __restrict__ out) {
  const size_t idx = (size_t)blockIdx.x * 256 + threadIdx.x;
  const int t = (int)(idx >> 11);
  const int h = (int)(idx & (NH - 1));
  float s = 0.f;
#pragma unroll
  for (int k = 0; k < NK; ++k)
    s += w_tk[t * NK + k] * yp[((size_t)(t * NK + k)) * NH + h];
  out[idx] = s;
}

// ---------------------------------------------------------------------------
extern "C" void kernel_launch(void* const* d_in, const int* in_sizes, int n_in,
                              void* d_out, int out_size, void* d_ws,
                              size_t ws_size, hipStream_t stream) {
  const float* x      = (const float*)d_in[0];
  const float* gate_w = (const float*)d_in[1];
  const float* wg     = (const float*)d_in[2];
  const float* wu     = (const float*)d_in[3];
  const float* wd     = (const float*)d_in[4];

  float* out        = (float*)d_out;
  float* logits_out = (float*)d_out + (size_t)NT * NH;

  char* ws = (char*)d_ws;
  int* cnt            = (int*)(ws + OFF_CNT);
  int* entries        = (int*)(ws + OFF_ENT);
  float* w_tk         = (float*)(ws + OFF_WTK);
  unsigned short* xb  = (unsigned short*)(ws + OFF_XB);
  unsigned short* act = (unsigned short*)(ws + OFF_ACT);
  float* yp           = (float*)(ws + OFF_YP);

  hipMemsetAsync(ws, 0, 1024, stream);  // zero expert counters

  router_kernel<<<NT, 256, 0, stream>>>(x, gate_w, logits_out, cnt, entries, w_tk, xb);
  phase1_mfma<<<dim3(NF / BN, 8, NE), 256, 0, stream>>>(xb, wg, wu, cnt, entries, act);
  phase2_mfma<<<dim3(NH / BN, 8, NE), 256, 0, stream>>>(act, wd, cnt, entries, yp);
  combine_kernel<<<(NT * NH) / 256, 256, 0, stream>>>(yp, w_tk, out);
}